// Round 1
// baseline (50.232 us; speedup 1.0000x reference)
//
#include <hip/hip_runtime.h>

typedef float2 c32;

__device__ __forceinline__ c32 cmul(c32 a, c32 b) {
    return make_float2(a.x * b.x - a.y * b.y, a.x * b.y + a.y * b.x);
}
__device__ __forceinline__ c32 cmad(c32 a, c32 b, c32 acc) {
    acc.x = fmaf(a.x, b.x, fmaf(-a.y, b.y, acc.x));
    acc.y = fmaf(a.x, b.y, fmaf(a.y, b.x, acc.y));
    return acc;
}

// ---------------- gate-matrix precompute (1 block, threads 0..4 active) ----

__device__ void mk_u3(float th, float ph, float la, c32 U[2][2]) {
    float ct = cosf(0.5f * th), st = sinf(0.5f * th);
    U[0][0] = make_float2(ct, 0.f);
    U[0][1] = make_float2(-cosf(la) * st, -sinf(la) * st);
    U[1][0] = make_float2(cosf(ph) * st, sinf(ph) * st);
    U[1][1] = make_float2(cosf(ph + la) * ct, sinf(ph + la) * ct);
}

__device__ void kron2(const c32 A[2][2], const c32 B[2][2], c32 K[4][4]) {
    for (int i0 = 0; i0 < 2; ++i0)
        for (int i1 = 0; i1 < 2; ++i1)
            for (int j0 = 0; j0 < 2; ++j0)
                for (int j1 = 0; j1 < 2; ++j1)
                    K[2 * i0 + i1][2 * j0 + j1] = cmul(A[i0][j0], B[i1][j1]);
}

__device__ void mat_lmul(const c32 G[4][4], c32 M[4][4]) {
    c32 T[4][4];
    for (int r = 0; r < 4; ++r)
        for (int c = 0; c < 4; ++c) {
            c32 acc = make_float2(0.f, 0.f);
            for (int k = 0; k < 4; ++k) acc = cmad(G[r][k], M[k][c], acc);
            T[r][c] = acc;
        }
    for (int r = 0; r < 4; ++r)
        for (int c = 0; c < 4; ++c) M[r][c] = T[r][c];
}

__device__ void swap_rows(c32 M[4][4], int r0, int r1) {
    for (int c = 0; c < 4; ++c) {
        c32 t = M[r0][c]; M[r0][c] = M[r1][c]; M[r1][c] = t;
    }
}

__global__ void build_gates_kernel(const float* __restrict__ w, c32* __restrict__ mats) {
    int t = threadIdx.x;
    if (t >= 5) return;
    const float* p = w + t * 15;
    c32 A[2][2], B[2][2], M[4][4], G[4][4];
    // u3(p0,p1,p2) on w0 ; u3(p3,p4,p5) on w1
    mk_u3(p[0], p[1], p[2], A);
    mk_u3(p[3], p[4], p[5], B);
    kron2(A, B, M);
    // CNOT(w0 -> w1): swap basis states |10>,|11>  (rows 2,3)
    swap_rows(M, 2, 3);
    // ry(p6) on w0  (x)  rz(p7) on w1
    {
        float c = cosf(0.5f * p[6]), s = sinf(0.5f * p[6]);
        A[0][0] = make_float2(c, 0.f);  A[0][1] = make_float2(-s, 0.f);
        A[1][0] = make_float2(s, 0.f);  A[1][1] = make_float2(c, 0.f);
        float cz = cosf(0.5f * p[7]), sz = sinf(0.5f * p[7]);
        B[0][0] = make_float2(cz, -sz); B[0][1] = make_float2(0.f, 0.f);
        B[1][0] = make_float2(0.f, 0.f); B[1][1] = make_float2(cz, sz);
        kron2(A, B, G);
        mat_lmul(G, M);
    }
    // CNOT(w1 -> w0): swap basis states |01>,|11>  (rows 1,3)
    swap_rows(M, 1, 3);
    // ry(p8) on w0  (x)  I
    {
        float c = cosf(0.5f * p[8]), s = sinf(0.5f * p[8]);
        A[0][0] = make_float2(c, 0.f);  A[0][1] = make_float2(-s, 0.f);
        A[1][0] = make_float2(s, 0.f);  A[1][1] = make_float2(c, 0.f);
        B[0][0] = make_float2(1.f, 0.f); B[0][1] = make_float2(0.f, 0.f);
        B[1][0] = make_float2(0.f, 0.f); B[1][1] = make_float2(1.f, 0.f);
        kron2(A, B, G);
        mat_lmul(G, M);
    }
    // CNOT(w0 -> w1)
    swap_rows(M, 2, 3);
    // u3(p9,p10,p11) on w0 ; u3(p12,p13,p14) on w1
    mk_u3(p[9], p[10], p[11], A);
    mk_u3(p[12], p[13], p[14], B);
    kron2(A, B, G);
    mat_lmul(G, M);
    for (int r = 0; r < 4; ++r)
        for (int c = 0; c < 4; ++c)
            mats[t * 16 + r * 4 + c] = M[r][c];
}

// ---------------- main simulator: 1 wave per batch state ------------------

__device__ __forceinline__ int swz(int i) { return i ^ (i >> 4); }

__global__ __launch_bounds__(256) void sim_kernel(const float* __restrict__ x,
                                                  const c32* __restrict__ gmats,
                                                  float* __restrict__ out) {
    __shared__ c32 S[4][256];
    __shared__ c32 GM[5][16];
    const int tid = threadIdx.x;
    const int wv = tid >> 6, lane = tid & 63;
    if (tid < 80) (&GM[0][0])[tid] = gmats[tid];
    const int b = blockIdx.x * 4 + wv;
    const float* xr = x + (size_t)b * 256;

    // load row, compute norm, write normalized real state into swizzled LDS
    float v0 = xr[lane], v1 = xr[lane + 64], v2 = xr[lane + 128], v3 = xr[lane + 192];
    float ss = v0 * v0 + v1 * v1 + v2 * v2 + v3 * v3;
#pragma unroll
    for (int o = 32; o; o >>= 1) ss += __shfl_xor(ss, o, 64);
    float inv = 1.0f / sqrtf(ss);
    S[wv][swz(lane)]       = make_float2(v0 * inv, 0.f);
    S[wv][swz(lane + 64)]  = make_float2(v1 * inv, 0.f);
    S[wv][swz(lane + 128)] = make_float2(v2 * inv, 0.f);
    S[wv][swz(lane + 192)] = make_float2(v3 * inv, 0.f);
    __syncthreads();

    // gate list: (layer param-set, bit positions p = 7 - wire)
    constexpr int g_li[25] = {0,0,0,0,0,0,0,0, 1,1,1,1,1,1,1,1, 2,2,2,2, 3,3,3,3, 4};
    constexpr int g_p0[25] = {7,5,3,1,6,4,2,0, 7,5,3,1,6,4,2,0, 5,1,7,3, 5,1,7,3, 5};
    constexpr int g_p1[25] = {6,4,2,0,5,3,1,7, 6,4,2,0,5,3,1,7, 3,7,5,1, 3,7,5,1, 1};

#pragma unroll
    for (int g = 0; g < 25; ++g) {
        const int p0 = g_p0[g], p1 = g_p1[g];
        const int lo = (p0 < p1) ? p0 : p1;
        const int hi = (p0 < p1) ? p1 : p0;
        // spread 6-bit lane index over the 6 free bit positions
        int t1   = ((lane & ~((1 << lo) - 1)) << 1) | (lane & ((1 << lo) - 1));
        int base = ((t1 & ~((1 << hi) - 1)) << 1) | (t1 & ((1 << hi) - 1));
        const int i00 = base;
        const int i01 = base | (1 << p1);
        const int i10 = base | (1 << p0);
        const int i11 = i10 | (1 << p1);
        c32 a0 = S[wv][swz(i00)];
        c32 a1 = S[wv][swz(i01)];
        c32 a2 = S[wv][swz(i10)];
        c32 a3 = S[wv][swz(i11)];
        const c32* M = GM[g_li[g]];
        c32 r0 = cmul(M[0],  a0); r0 = cmad(M[1],  a1, r0); r0 = cmad(M[2],  a2, r0); r0 = cmad(M[3],  a3, r0);
        c32 r1 = cmul(M[4],  a0); r1 = cmad(M[5],  a1, r1); r1 = cmad(M[6],  a2, r1); r1 = cmad(M[7],  a3, r1);
        c32 r2 = cmul(M[8],  a0); r2 = cmad(M[9],  a1, r2); r2 = cmad(M[10], a2, r2); r2 = cmad(M[11], a3, r2);
        c32 r3 = cmul(M[12], a0); r3 = cmad(M[13], a1, r3); r3 = cmad(M[14], a2, r3); r3 = cmad(M[15], a3, r3);
        S[wv][swz(i00)] = r0;
        S[wv][swz(i01)] = r1;
        S[wv][swz(i10)] = r2;
        S[wv][swz(i11)] = r3;
        __syncthreads();
    }

    // expectations: qubit 2 -> bit 5, qubit 6 -> bit 1
    float e0 = 0, e1 = 0, e2 = 0, e3 = 0, e4 = 0, e5 = 0, e6 = 0, e7 = 0, e8 = 0;
#pragma unroll
    for (int k = 0; k < 4; ++k) {
        const int i = lane + 64 * k;
        c32 a = S[wv][swz(i)];
        float pr = a.x * a.x + a.y * a.y;
        const int b2 = (i >> 5) & 1, b6 = (i >> 1) & 1;
        float z2 = 1.f - 2.f * (float)b2, z6 = 1.f - 2.f * (float)b6;
        e2 += pr * z2;
        e5 += pr * z6;
        e8 += pr * z2 * z6;
        if (!b2) {
            c32 p = S[wv][swz(i | 32)];
            float cr = a.x * p.x + a.y * p.y;   // Re(conj(a)*p)
            float ci = a.x * p.y - a.y * p.x;   // Im(conj(a)*p)
            e0 += 2.f * cr;
            e1 += 2.f * ci;
            c32 d = S[wv][swz(i ^ 34)];         // flip bits 5 and 1
            float dr = a.x * d.x + a.y * d.y;
            e6 += 2.f * dr;
            e7 += (2.f * (float)b6 - 1.f) * 2.f * dr;
        }
        if (!b6) {
            c32 p = S[wv][swz(i | 2)];
            float cr = a.x * p.x + a.y * p.y;
            float ci = a.x * p.y - a.y * p.x;
            e3 += 2.f * cr;
            e4 += 2.f * ci;
        }
    }
    float e[9] = {e0, e1, e2, e3, e4, e5, e6, e7, e8};
#pragma unroll
    for (int m = 0; m < 9; ++m) {
        float s = e[m];
#pragma unroll
        for (int o = 32; o; o >>= 1) s += __shfl_xor(s, o, 64);
        e[m] = s;
    }
    if (lane == 0) {
#pragma unroll
        for (int m = 0; m < 9; ++m) out[b * 9 + m] = e[m];
    }
}

extern "C" void kernel_launch(void* const* d_in, const int* in_sizes, int n_in,
                              void* d_out, int out_size, void* d_ws, size_t ws_size,
                              hipStream_t stream) {
    const float* x = (const float*)d_in[0];
    const float* w = (const float*)d_in[1];
    float* out = (float*)d_out;
    c32* mats = (c32*)d_ws;

    hipLaunchKernelGGL(build_gates_kernel, dim3(1), dim3(64), 0, stream, w, mats);

    const int batch = in_sizes[0] / 256;   // 8192
    const int nblocks = batch / 4;         // 4 states (waves) per block
    hipLaunchKernelGGL(sim_kernel, dim3(nblocks), dim3(256), 0, stream, x, mats, out);
}